// Round 2
// baseline (3388.089 us; speedup 1.0000x reference)
//
#include <hip/hip_runtime.h>

// Program-guided CNN executor — split-bf16 MFMA, oc-split + K-split persistent
// version. B=32, T=30, C=128, 14x14 (P=196). 256 WGs = 32 b x 4 oc-tiles (mt)
// x 2 K-halves (kh). Each WG (512 thr, 8 waves) computes a 32-oc PARTIAL conv
// over half the input channels; the two kh partials are summed (+ReLU) by
// consumers at staging time. The 8 WGs of one b sync between conv stages via
// monotone atomic barriers (8 arrivals, agent scope, relaxed poll + one
// acquire load). Conv = implicit GEMM over 9 taps; fp32 = WhXh + WhXl + WlXh
// (3x bf16 MFMA). Next chunk's weights prefetched into double-buffered regs.
// conv_run is templated on staging MODE (0=raw single, 1=pair, 2=pair+pair
// concat) so all staging branches are compile-time (avoids clang-22 ICE seen
// with runtime-nullable staging pointers).

#define NSTEP 30
#define CD 147456            // 128*128*9
#define P 196
#define FSZ 25088            // 128*196 floats per (b, buffer)
#define LROW 18              // LDS row: 16 packed u32 (hi|lo) + 2 pad
#define LBUF (272*LROW)

typedef __attribute__((ext_vector_type(8))) short short8;
typedef __attribute__((ext_vector_type(16))) float f32x16;

__constant__ int KIND_TBL[44] = {
  0,0,0,0,1,3,3,3,3,3, 2,2,2,2,2,2,2,2,2,2,
  2,2,2,2,2,2,3,3,3,2, 2,2,2,2,2,2,2,2,2,2, 2,2,3,2};
__constant__ int MIDX_TBL[44] = {
  0,0,0,0,0,0,1,2,3,4, 1,2,3,4,5,6,7,8,9,10,
  11,12,13,14,15,16,5,6,7,17, 18,19,20,21,22,23,24,25,26,27, 28,29,8,30};

__device__ __forceinline__ uint32_t bf16_rne(float x) {
  uint32_t u = __float_as_uint(x);
  return (u + 0x7fffu + ((u >> 16) & 1u)) >> 16;
}
__device__ __forceinline__ uint32_t pack_hl(float x) {
  uint32_t h = bf16_rne(x);
  float rest = x - __uint_as_float(h << 16);
  uint32_t l = bf16_rne(rest);
  return (h << 16) | l;
}
__device__ __forceinline__ float ld_sc0(const float* p) {  // L1-bypass agent load
  return __hip_atomic_load(p, __ATOMIC_RELAXED, __HIP_MEMORY_SCOPE_AGENT);
}

// Per-b barrier among the 8 WGs of one batch element (monotone counter).
// Relaxed polling (no per-poll L2 invalidate); one acquire load at exit.
__device__ __forceinline__ void bbar(int* __restrict__ ctr, int target) {
  __syncthreads();
  if (threadIdx.x == 0) {
    __hip_atomic_fetch_add(ctr, 1, __ATOMIC_RELEASE, __HIP_MEMORY_SCOPE_AGENT);
    while (__hip_atomic_load(ctr, __ATOMIC_RELAXED, __HIP_MEMORY_SCOPE_AGENT) < target)
      __builtin_amdgcn_s_sleep(2);
    (void)__hip_atomic_load(ctr, __ATOMIC_ACQUIRE, __HIP_MEMORY_SCOPE_AGENT);
  }
  __syncthreads();
}

// Weight repack (unchanged layout): per (chunk C, tap) 8KB block:
// [mt(4)][hl(2)][lane(64)][bf16x8]. lane=(oc%32)|((ic8)<<5).
__global__ void __launch_bounds__(256) repack_kernel(
    const float* __restrict__ sw1, const float* __restrict__ sw2,
    const float* __restrict__ mu, const float* __restrict__ mb,
    uint32_t* __restrict__ Wp)
{
  const int blk = blockIdx.x;
  const int C = blk / 9, tap = blk % 9;
  const float* src; int nic, lc;
  if (C < 64)       { src = sw1; nic = 1024; lc = C; }
  else if (C < 72)  { src = sw2; nic = 128;  lc = C - 64; }
  else if (C < 568) { int u = (C - 72) >> 4, r = (C - 72) & 15;
                      src = mu + (size_t)u * 2 * CD + (size_t)(r >> 3) * CD;
                      nic = 128; lc = r & 7; }
  else              { int j = (C - 568) >> 5, r = (C - 568) & 31;
                      const float* base = mb + (size_t)j * 4 * CD;
                      if (r < 16)      { src = base;                  nic = 256; lc = r; }
                      else if (r < 24) { src = base + 2 * (size_t)CD; nic = 128; lc = r - 16; }
                      else             { src = base + 3 * (size_t)CD; nic = 128; lc = r - 24; } }
  const int mt = threadIdx.x >> 6, lane = threadIdx.x & 63;
  const int oc = mt * 32 + (lane & 31);
  const int ic0 = lc * 16 + (lane >> 5) * 8;
  uint32_t hw[4], lw[4];
#pragma unroll
  for (int pr = 0; pr < 4; ++pr) {
    uint32_t hh[2], ll[2];
#pragma unroll
    for (int e = 0; e < 2; ++e) {
      float x = src[((size_t)oc * nic + (ic0 + pr * 2 + e)) * 9 + tap];
      uint32_t h = bf16_rne(x);
      float rest = x - __uint_as_float(h << 16);
      hh[e] = h; ll[e] = bf16_rne(rest);
    }
    hw[pr] = hh[0] | (hh[1] << 16);
    lw[pr] = ll[0] | (ll[1] << 16);
  }
  uint32_t* dstb = Wp + (size_t)blk * 2048;
  *(uint4*)(dstb + (mt * 2 + 0) * 256 + lane * 4) = make_uint4(hw[0], hw[1], hw[2], hw[3]);
  *(uint4*)(dstb + (mt * 2 + 1) * 256 + lane * 4) = make_uint4(lw[0], lw[1], lw[2], lw[3]);
}

union BU { uint32_t u[4]; uint4 v; short8 s8; };

__device__ __forceinline__ void load_wchunk(const uint32_t* __restrict__ wb,
                                            BU* wh, BU* wl) {
#pragma unroll
  for (int t = 0; t < 9; ++t) {
    wh[t].v = *(const uint4*)(wb + t * 2048);
    wl[t].v = *(const uint4*)(wb + t * 2048 + 256);
  }
}

__device__ __forceinline__ void mfma_chunk(const uint32_t* __restrict__ sb,
                                           int pwbase, const BU* wh, const BU* wl,
                                           f32x16& acc) {
  const int TAPOFF[9] = {0, 1, 2, 16, 17, 18, 32, 33, 34};
#pragma unroll
  for (int tap = 0; tap < 9; ++tap) {
    const int pw = pwbase + TAPOFF[tap] * LROW;
    uint2 q0 = *(const uint2*)(sb + pw);
    uint2 q1 = *(const uint2*)(sb + pw + 2);
    uint2 q2 = *(const uint2*)(sb + pw + 4);
    uint2 q3 = *(const uint2*)(sb + pw + 6);
    BU Bh, Bl;
    Bh.u[0] = __builtin_amdgcn_perm(q0.y, q0.x, 0x07060302u);
    Bh.u[1] = __builtin_amdgcn_perm(q1.y, q1.x, 0x07060302u);
    Bh.u[2] = __builtin_amdgcn_perm(q2.y, q2.x, 0x07060302u);
    Bh.u[3] = __builtin_amdgcn_perm(q3.y, q3.x, 0x07060302u);
    Bl.u[0] = __builtin_amdgcn_perm(q0.y, q0.x, 0x05040100u);
    Bl.u[1] = __builtin_amdgcn_perm(q1.y, q1.x, 0x05040100u);
    Bl.u[2] = __builtin_amdgcn_perm(q2.y, q2.x, 0x05040100u);
    Bl.u[3] = __builtin_amdgcn_perm(q3.y, q3.x, 0x05040100u);
    acc = __builtin_amdgcn_mfma_f32_32x32x16_bf16(wh[tap].s8, Bh.s8, acc, 0, 0, 0);
    acc = __builtin_amdgcn_mfma_f32_32x32x16_bf16(wh[tap].s8, Bl.s8, acc, 0, 0, 0);
    acc = __builtin_amdgcn_mfma_f32_32x32x16_bf16(wl[tap].s8, Bh.s8, acc, 0, 0, 0);
  }
}

// Compile-time staging modes:
//  MODE 0: raw single input (stem1, external feats)
//  MODE 1: kh-pair input, value = relu(A+B)
//  MODE 2: concat of two kh-pairs (binary conv stage 1), split at 'split'
template<int MODE>
__device__ __forceinline__ void stage_load(
    const float* __restrict__ in0A, const float* __restrict__ in0B,
    const float* __restrict__ in1A, const float* __restrict__ in1B,
    int split, int cn, int ic16, const int* imgoff, float* sv)
{
  if (MODE == 0) {
    const float* sA = in0A + (size_t)(cn * 16 + ic16) * P;
#pragma unroll
    for (int i = 0; i < 9; ++i) {
      int off = imgoff[i];
      sv[i] = (off >= 0) ? sA[off] : 0.f;
    }
  } else if (MODE == 1) {
    size_t o = (size_t)(cn * 16 + ic16) * P;
    const float* sA = in0A + o;
    const float* sB = in0B + o;
#pragma unroll
    for (int i = 0; i < 9; ++i) {
      int off = imgoff[i];
      sv[i] = (off >= 0) ? fmaxf(ld_sc0(sA + off) + ld_sc0(sB + off), 0.f) : 0.f;
    }
  } else {
    const float* sA; const float* sB;
    if (cn < split) {
      size_t o = (size_t)(cn * 16 + ic16) * P;
      sA = in0A + o; sB = in0B + o;
    } else {
      size_t o = (size_t)((cn - split) * 16 + ic16) * P;
      sA = in1A + o; sB = in1B + o;
    }
#pragma unroll
    for (int i = 0; i < 9; ++i) {
      int off = imgoff[i];
      sv[i] = (off >= 0) ? fmaxf(ld_sc0(sA + off) + ld_sc0(sB + off), 0.f) : 0.f;
    }
  }
}

// One PARTIAL conv3x3 (n chunks of 16 ic starting at cbeg, this WG's 32-oc
// slice mt) for one b. Writes raw partial sums (bias added iff bias!=null);
// ReLU is applied by consumers when summing the kh pair.
template<int MODE>
__device__ __forceinline__ void conv_run(
    uint32_t sbuf[2][LBUF],
    const float* __restrict__ in0A, const float* __restrict__ in0B,
    const float* __restrict__ in1A, const float* __restrict__ in1B,
    int split, int cbeg, int n,
    int C0, int mt,
    const uint32_t* __restrict__ Wp, const float* __restrict__ bias,
    float* __restrict__ dst, float* __restrict__ dst2, float* __restrict__ zb,
    const int* imgoff)
{
  const int tid = threadIdx.x;
  const int w = tid >> 6, lane = tid & 63, l31 = lane & 31, kq = lane >> 5;
  const int ic16 = tid >> 5, pl = tid & 31;
  const int pwbase = (32 * w + l31) * LROW + kq * 8;
  const bool cw = (w < 7);
  const uint32_t* wbase = Wp + (size_t)C0 * 9 * 2048 + (mt * 2) * 256 + lane * 4;

  f32x16 acc;
#pragma unroll
  for (int i = 0; i < 16; ++i) acc[i] = 0.f;

  BU whA[9], wlA[9], whB[9], wlB[9];
  if (cw) load_wchunk(wbase + (size_t)cbeg * 9 * 2048, whA, wlA);
  { // stage chunk cbeg
    float sv[9];
    stage_load<MODE>(in0A, in0B, in1A, in1B, split, cbeg, ic16, imgoff, sv);
#pragma unroll
    for (int i = 0; i < 9; ++i) {
      int p = pl + 32 * i;
      if (p < 272) sbuf[0][p * LROW + ic16] = pack_hl(sv[i]);
    }
  }
  __syncthreads();

  int k = 0;
  while (true) {
    { // even chunk: consume A, prefetch into B
      const bool more = (k + 1 < n);
      float sv[9];
      if (more) {
        stage_load<MODE>(in0A, in0B, in1A, in1B, split, cbeg + k + 1, ic16, imgoff, sv);
        if (cw) load_wchunk(wbase + (size_t)(cbeg + k + 1) * 9 * 2048, whB, wlB);
      }
      if (cw) mfma_chunk(&sbuf[k & 1][0], pwbase, whA, wlA, acc);
      if (more) {
#pragma unroll
        for (int i = 0; i < 9; ++i) {
          int p = pl + 32 * i;
          if (p < 272) sbuf[(k + 1) & 1][p * LROW + ic16] = pack_hl(sv[i]);
        }
      }
      __syncthreads();
      if (++k >= n) break;
    }
    { // odd chunk: consume B, prefetch into A
      const bool more = (k + 1 < n);
      float sv[9];
      if (more) {
        stage_load<MODE>(in0A, in0B, in1A, in1B, split, cbeg + k + 1, ic16, imgoff, sv);
        if (cw) load_wchunk(wbase + (size_t)(cbeg + k + 1) * 9 * 2048, whA, wlA);
      }
      if (cw) mfma_chunk(&sbuf[k & 1][0], pwbase, whB, wlB, acc);
      if (more) {
#pragma unroll
        for (int i = 0; i < 9; ++i) {
          int p = pl + 32 * i;
          if (p < 272) sbuf[(k + 1) & 1][p * LROW + ic16] = pack_hl(sv[i]);
        }
      }
      __syncthreads();
      if (++k >= n) break;
    }
  }

  if (cw) {
    const int ox = l31 & 15, oy = 2 * w + (l31 >> 4);
    if (ox < 14) {
#pragma unroll
      for (int reg = 0; reg < 16; ++reg) {
        int row = (reg & 3) + 8 * (reg >> 2) + 4 * kq;
        int oc = mt * 32 + row;
        float v = acc[reg];
        if (bias) v += bias[row];
        dst[(size_t)oc * P + oy * 14 + ox] = v;
        if (dst2) dst2[(size_t)oc * P + oy * 14 + ox] = v;
        if (zb)   zb[(size_t)oc * P + oy * 14 + ox] = 0.f;
      }
    }
  }
}

__global__ void __launch_bounds__(512, 1) persist_kernel(
    const float* __restrict__ feats, const int* __restrict__ progs,
    const float* __restrict__ sb1, const float* __restrict__ sb2,
    const uint32_t* __restrict__ Wp,
    float* __restrict__ featA, float* __restrict__ featB,
    float* __restrict__ outbA, float* __restrict__ outbB,
    float* __restrict__ savedA, float* __restrict__ savedB,
    float* __restrict__ h1A, float* __restrict__ h1B,
    float* __restrict__ h2A, float* __restrict__ h2B,
    int* __restrict__ ctr)
{
  __shared__ uint32_t s_act[2][LBUF];
  const int tid = threadIdx.x;
  // b = bid & 31 -> all 8 slices of one b share bid%8, i.e. one XCD under
  // round-robin dispatch (locality heuristic only; correctness via agent ops).
  const int b = blockIdx.x & 31;
  const int slice = blockIdx.x >> 5;
  const int mt = slice & 3;
  const int kh = slice >> 2;
  const size_t bo = (size_t)b * FSZ;
  int* myctr = ctr + b * 32;
  int phase = 0;

  float* featP  = kh ? featB  : featA;
  float* outbP  = kh ? outbB  : outbA;
  float* savedP = kh ? savedB : savedA;
  float* h1P    = kh ? h1B    : h1A;
  float* h2P    = kh ? h2B    : h2A;
  const float* bias1 = kh ? nullptr : sb1 + mt * 32;
  const float* bias2 = kh ? nullptr : sb2 + mt * 32;

  int imgoff[9];
#pragma unroll
  for (int i = 0; i < 9; ++i) {
    int p = (tid & 31) + 32 * i;
    int row = p >> 4, col = p & 15;
    imgoff[i] = (p < 272 && row >= 1 && row <= 14 && col >= 1 && col <= 14)
                ? (row - 1) * 14 + (col - 1) : -1;
  }

  // stem1: raw feats (1024 ic, 64 chunks -> 32 per kh) -> h1 pair
  conv_run<0>(s_act, feats + (size_t)b * 1024 * P, nullptr, nullptr, nullptr,
              1 << 28, kh * 32, 32, 0, mt, Wp, bias1,
              h1P + bo, nullptr, nullptr, imgoff);
  bbar(myctr, ++phase * 8);
  // stem2: h1 pair -> feat pair (+ outb pair init, zero saved partial)
  conv_run<1>(s_act, h1A + bo, h1B + bo, nullptr, nullptr, 1 << 28,
              kh * 4, 4, 64, mt, Wp, bias2,
              featP + bo, outbP + bo, savedP + bo, imgoff);
  bbar(myctr, ++phase * 8);

  for (int s = 0; s < NSTEP; ++s) {
    int tok = progs[b * NSTEP + (NSTEP - 1 - s)];
    int kind = KIND_TBL[tok], mi = MIDX_TBL[tok];
    if (kind == 0) continue;
    if (kind == 1) {                 // scene: saved <- out (own partial); out <- unary0(feat)
      const size_t so = bo + (size_t)mt * 32 * P;
      for (int i = tid; i < 32 * P; i += 512)
        savedP[so + i] = outbP[so + i];   // own slice: plain loads/stores
      int C0 = 72 + mi * 16;
      conv_run<1>(s_act, featA + bo, featB + bo, nullptr, nullptr, 1 << 28,
                  kh * 4, 4, C0, mt, Wp, nullptr, h1P + bo, nullptr, nullptr, imgoff);
      bbar(myctr, ++phase * 8);
      conv_run<1>(s_act, h1A + bo, h1B + bo, nullptr, nullptr, 1 << 28,
                  kh * 4, 4, C0 + 8, mt, Wp, nullptr, outbP + bo, nullptr, nullptr, imgoff);
      bbar(myctr, ++phase * 8);
    } else if (kind == 2) {          // unary
      int C0 = 72 + mi * 16;
      conv_run<1>(s_act, outbA + bo, outbB + bo, nullptr, nullptr, 1 << 28,
                  kh * 4, 4, C0, mt, Wp, nullptr, h1P + bo, nullptr, nullptr, imgoff);
      bbar(myctr, ++phase * 8);
      conv_run<1>(s_act, h1A + bo, h1B + bo, nullptr, nullptr, 1 << 28,
                  kh * 4, 4, C0 + 8, mt, Wp, nullptr, outbP + bo, nullptr, nullptr, imgoff);
      bbar(myctr, ++phase * 8);
    } else {                         // binary: concat(out, saved) = 16 chunks, split 8/8
      int C0 = 568 + mi * 32;
      conv_run<2>(s_act, outbA + bo, outbB + bo, savedA + bo, savedB + bo, 8,
                  kh * 8, 8, C0, mt, Wp, nullptr, h1P + bo, nullptr, nullptr, imgoff);
      bbar(myctr, ++phase * 8);
      conv_run<1>(s_act, h1A + bo, h1B + bo, nullptr, nullptr, 1 << 28,
                  kh * 4, 4, C0 + 16, mt, Wp, nullptr, h2P + bo, nullptr, nullptr, imgoff);
      bbar(myctr, ++phase * 8);
      conv_run<1>(s_act, h2A + bo, h2B + bo, nullptr, nullptr, 1 << 28,
                  kh * 4, 4, C0 + 24, mt, Wp, nullptr, outbP + bo, nullptr, nullptr, imgoff);
      bbar(myctr, ++phase * 8);
    }
  }
}

// ---- tail ----
__global__ void __launch_bounds__(256) cls_pool_kernel(
    const float* __restrict__ xA, const float* __restrict__ xB,
    const float* __restrict__ Wc, const float* __restrict__ bc,
    float* __restrict__ hB)
{
  const int b = blockIdx.y, og = blockIdx.x;
  const int oc0 = og * 64;
  __shared__ float s[16 * P];
  const float* xbA = xA + (size_t)b * FSZ;
  const float* xbB = xB + (size_t)b * FSZ;
  const int tid = threadIdx.x;
  float acc[13][4];
#pragma unroll
  for (int k = 0; k < 13; ++k) { acc[k][0] = acc[k][1] = acc[k][2] = acc[k][3] = 0.f; }
  for (int c0 = 0; c0 < 128; c0 += 16) {
    __syncthreads();
    for (int i = tid; i < 16 * P; i += 256)
      s[i] = fmaxf(xbA[(size_t)c0 * P + i] + xbB[(size_t)c0 * P + i], 0.f);
    __syncthreads();
#pragma unroll
    for (int k = 0; k < 13; ++k) {
      const int idx = k * 256 + tid;
      if (idx < 64 * 49) {
        const int oc = oc0 + idx / 49, pp = idx % 49;
        const int py = pp / 7, px = pp % 7;
        const int b0 = 2 * py * 14 + 2 * px, b1 = b0 + 14;
        const float* wr = Wc + (size_t)oc * 128 + c0;
#pragma unroll
        for (int ic = 0; ic < 16; ++ic) {
          const float w = wr[ic];
          const float* sp = s + ic * P;
          const float2 r0 = *(const float2*)(sp + b0);
          const float2 r1 = *(const float2*)(sp + b1);
          acc[k][0] = fmaf(w, r0.x, acc[k][0]);
          acc[k][1] = fmaf(w, r0.y, acc[k][1]);
          acc[k][2] = fmaf(w, r1.x, acc[k][2]);
          acc[k][3] = fmaf(w, r1.y, acc[k][3]);
        }
      }
    }
  }
#pragma unroll
  for (int k = 0; k < 13; ++k) {
    const int idx = k * 256 + tid;
    if (idx < 64 * 49) {
      const int oc = oc0 + idx / 49, pp = idx % 49;
      const float m = fmaxf(fmaxf(acc[k][0], acc[k][1]), fmaxf(acc[k][2], acc[k][3]));
      hB[(size_t)b * 25088 + (size_t)oc * 49 + pp] = fmaxf(m + bc[oc], 0.f);
    }
  }
}

__global__ void __launch_bounds__(256) transpose_kernel(
    const float* __restrict__ hB, float* __restrict__ hT)
{
  __shared__ float t[256 * 33];
  const int k0 = blockIdx.x * 256;
  const int tid = threadIdx.x;
  for (int b = 0; b < 32; ++b)
    t[tid * 33 + b] = hB[(size_t)b * 25088 + k0 + tid];
  __syncthreads();
  for (int i = tid; i < 256 * 32; i += 256) {
    const int k = i >> 5, b = i & 31;
    hT[(size_t)(k0 + k) * 32 + b] = t[k * 33 + b];
  }
}

// 256 WGs: 4 oc each, 2-way K split, LDS pair-reduce.
__global__ void __launch_bounds__(256) fc1_kernel(
    const float* __restrict__ hT, const float* __restrict__ W,
    const float* __restrict__ bias, float* __restrict__ o)
{
  const int b = threadIdx.x & 31, j = threadIdx.x >> 5;   // j 0..7
  const int oc = blockIdx.x * 4 + (j & 3);
  const int kh = j >> 2;
  const float* wr = W + (size_t)oc * 25088 + (size_t)kh * 12544;
  const float* ht = hT + (size_t)kh * 12544 * 32;
  float acc = 0.f;
  for (int k = 0; k < 12544; k += 4) {
    const float4 w4 = *(const float4*)(wr + k);
    acc = fmaf(ht[(size_t)(k + 0) * 32 + b], w4.x, acc);
    acc = fmaf(ht[(size_t)(k + 1) * 32 + b], w4.y, acc);
    acc = fmaf(ht[(size_t)(k + 2) * 32 + b], w4.z, acc);
    acc = fmaf(ht[(size_t)(k + 3) * 32 + b], w4.w, acc);
  }
  __shared__ float red[8][32];
  red[j][b] = acc;
  __syncthreads();
  if (j < 4)
    o[(size_t)b * 1024 + oc] = fmaxf(red[j][b] + red[j + 4][b] + bias[oc], 0.f);
}

__global__ void __launch_bounds__(256) fc2_kernel(
    const float* __restrict__ h, const float* __restrict__ W,
    const float* __restrict__ bias, float* __restrict__ out)
{
  const int i = blockIdx.x * 256 + threadIdx.x;
  const int b = i >> 5, oo = i & 31;
  const float* wr = W + (size_t)oo * 1024;
  const float* hr = h + (size_t)b * 1024;
  float acc = bias[oo];
  for (int k = 0; k < 1024; k += 4) {
    const float4 w4 = *(const float4*)(wr + k);
    const float4 h4 = *(const float4*)(hr + k);
    acc = fmaf(h4.x, w4.x, acc);
    acc = fmaf(h4.y, w4.y, acc);
    acc = fmaf(h4.z, w4.z, acc);
    acc = fmaf(h4.w, w4.w, acc);
  }
  out[i] = acc;
}

extern "C" void kernel_launch(void* const* d_in, const int* in_sizes, int n_in,
                              void* d_out, int out_size, void* d_ws, size_t ws_size,
                              hipStream_t stream) {
  const float* feats   = (const float*)d_in[0];
  const int*   progs   = (const int*)  d_in[1];
  const float* stem_w1 = (const float*)d_in[2];
  const float* stem_b1 = (const float*)d_in[3];
  const float* stem_w2 = (const float*)d_in[4];
  const float* stem_b2 = (const float*)d_in[5];
  const float* mem_u   = (const float*)d_in[6];
  const float* mem_b   = (const float*)d_in[7];
  const float* cls_w   = (const float*)d_in[8];
  const float* cls_b   = (const float*)d_in[9];
  const float* fc1_w   = (const float*)d_in[10];
  const float* fc1_b   = (const float*)d_in[11];
  const float* fc2_w   = (const float*)d_in[12];
  const float* fc2_b   = (const float*)d_in[13];

  float* ws = (float*)d_ws;
  const size_t F = (size_t)32 * FSZ;
  float*    featA  = ws + 0 * F;
  float*    featB  = ws + 1 * F;
  float*    outbA  = ws + 2 * F;
  float*    outbB  = ws + 3 * F;
  float*    savedA = ws + 4 * F;
  float*    savedB = ws + 5 * F;
  float*    h1A    = ws + 6 * F;
  float*    h1B    = ws + 7 * F;
  float*    h2A    = ws + 8 * F;
  float*    h2B    = ws + 9 * F;
  uint32_t* Wp    = (uint32_t*)(ws + 10 * F);         // 7704 x 8KB = 63.1 MB
  int*      ctr   = (int*)(Wp + (size_t)7704 * 2048); // 32 b x 32-int lines

  hipMemsetAsync(ctr, 0, 32 * 32 * sizeof(int), stream);

  repack_kernel<<<dim3(7704), dim3(256), 0, stream>>>(stem_w1, stem_w2, mem_u, mem_b, Wp);

  persist_kernel<<<dim3(256), dim3(512), 0, stream>>>(
      feats, progs, stem_b1, stem_b2, Wp,
      featA, featB, outbA, outbB, savedA, savedB, h1A, h1B, h2A, h2B, ctr);

  float* hB   = h1A;
  float* hT   = h2A;
  float* fc1o = savedA;
  cls_pool_kernel<<<dim3(8, 32), dim3(256), 0, stream>>>(outbA, outbB, cls_w, cls_b, hB);
  transpose_kernel<<<dim3(98), dim3(256), 0, stream>>>(hB, hT);
  fc1_kernel<<<dim3(256), dim3(256), 0, stream>>>(hT, fc1_w, fc1_b, fc1o);
  fc2_kernel<<<dim3(4), dim3(256), 0, stream>>>(fc1o, fc2_w, fc2_b, (float*)d_out);
}

// Round 3
// 2944.887 us; speedup vs baseline: 1.1505x; 1.1505x over previous
//
#include <hip/hip_runtime.h>

// Program-guided CNN executor — split-bf16 MFMA, oc-split + K-split persistent
// version. B=32, T=30, C=128, 14x14 (P=196). 256 WGs = 32 b x 4 oc-tiles (mt)
// x 2 K-halves (kh). Each WG (512 thr, 8 waves) computes a 32-oc PARTIAL conv
// over half the input channels; the two kh partials are summed (+ReLU) by
// consumers at staging time.
//
// Cross-WG memory protocol (the R3 change): all cross-WG activation traffic is
// WRITE-THROUGH (agent-scope relaxed atomic stores -> sc0 sc1, straight to L3)
// and L3-direct loads (sc0 sc1). Barriers are monotone counters with RELAXED
// fetch_add + relaxed poll: __syncthreads() before the add drains vmcnt(0), so
// stores are at the coherence point before the flag. NO release/acquire =>
// no buffer_wbl2 / buffer_inv per stage (R2 profiling showed those full-L2
// flushes were a ~38us/stage fixed cost and evicted the weight cache).
// Conv = implicit GEMM over 9 taps; fp32 = WhXh + WhXl + WlXh (3x bf16 MFMA).

#define NSTEP 30
#define CD 147456            // 128*128*9
#define P 196
#define FSZ 25088            // 128*196 floats per (b, buffer)
#define LROW 18              // LDS row: 16 packed u32 (hi|lo) + 2 pad
#define LBUF (272*LROW)

typedef __attribute__((ext_vector_type(8))) short short8;
typedef __attribute__((ext_vector_type(16))) float f32x16;

__constant__ int KIND_TBL[44] = {
  0,0,0,0,1,3,3,3,3,3, 2,2,2,2,2,2,2,2,2,2,
  2,2,2,2,2,2,3,3,3,2, 2,2,2,2,2,2,2,2,2,2, 2,2,3,2};
__constant__ int MIDX_TBL[44] = {
  0,0,0,0,0,0,1,2,3,4, 1,2,3,4,5,6,7,8,9,10,
  11,12,13,14,15,16,5,6,7,17, 18,19,20,21,22,23,24,25,26,27, 28,29,8,30};

__device__ __forceinline__ uint32_t bf16_rne(float x) {
  uint32_t u = __float_as_uint(x);
  return (u + 0x7fffu + ((u >> 16) & 1u)) >> 16;
}
__device__ __forceinline__ uint32_t pack_hl(float x) {
  uint32_t h = bf16_rne(x);
  float rest = x - __uint_as_float(h << 16);
  uint32_t l = bf16_rne(rest);
  return (h << 16) | l;
}
// L3-direct (sc0 sc1) load/store: bypass L1+L2, coherent at agent scope.
__device__ __forceinline__ float ld_sc0(const float* p) {
  return __hip_atomic_load(p, __ATOMIC_RELAXED, __HIP_MEMORY_SCOPE_AGENT);
}
__device__ __forceinline__ void st_sc(float* p, float v) {
  __hip_atomic_store(p, v, __ATOMIC_RELAXED, __HIP_MEMORY_SCOPE_AGENT);
}

// Per-b barrier among the 8 WGs of one batch element (monotone counter).
// RELAXED add + RELAXED poll: data was written write-through (st_sc) and
// __syncthreads() drains vmcnt before the add, so no cache maintenance needed.
__device__ __forceinline__ void bbar(int* __restrict__ ctr, int target) {
  __syncthreads();
  if (threadIdx.x == 0) {
    __hip_atomic_fetch_add(ctr, 1, __ATOMIC_RELAXED, __HIP_MEMORY_SCOPE_AGENT);
    while (__hip_atomic_load(ctr, __ATOMIC_RELAXED, __HIP_MEMORY_SCOPE_AGENT) < target)
      __builtin_amdgcn_s_sleep(2);
  }
  __syncthreads();
}

// Weight repack (unchanged layout): per (chunk C, tap) 8KB block:
// [mt(4)][hl(2)][lane(64)][bf16x8]. lane=(oc%32)|((ic8)<<5).
__global__ void __launch_bounds__(256) repack_kernel(
    const float* __restrict__ sw1, const float* __restrict__ sw2,
    const float* __restrict__ mu, const float* __restrict__ mb,
    uint32_t* __restrict__ Wp)
{
  const int blk = blockIdx.x;
  const int C = blk / 9, tap = blk % 9;
  const float* src; int nic, lc;
  if (C < 64)       { src = sw1; nic = 1024; lc = C; }
  else if (C < 72)  { src = sw2; nic = 128;  lc = C - 64; }
  else if (C < 568) { int u = (C - 72) >> 4, r = (C - 72) & 15;
                      src = mu + (size_t)u * 2 * CD + (size_t)(r >> 3) * CD;
                      nic = 128; lc = r & 7; }
  else              { int j = (C - 568) >> 5, r = (C - 568) & 31;
                      const float* base = mb + (size_t)j * 4 * CD;
                      if (r < 16)      { src = base;                  nic = 256; lc = r; }
                      else if (r < 24) { src = base + 2 * (size_t)CD; nic = 128; lc = r - 16; }
                      else             { src = base + 3 * (size_t)CD; nic = 128; lc = r - 24; } }
  const int mt = threadIdx.x >> 6, lane = threadIdx.x & 63;
  const int oc = mt * 32 + (lane & 31);
  const int ic0 = lc * 16 + (lane >> 5) * 8;
  uint32_t hw[4], lw[4];
#pragma unroll
  for (int pr = 0; pr < 4; ++pr) {
    uint32_t hh[2], ll[2];
#pragma unroll
    for (int e = 0; e < 2; ++e) {
      float x = src[((size_t)oc * nic + (ic0 + pr * 2 + e)) * 9 + tap];
      uint32_t h = bf16_rne(x);
      float rest = x - __uint_as_float(h << 16);
      hh[e] = h; ll[e] = bf16_rne(rest);
    }
    hw[pr] = hh[0] | (hh[1] << 16);
    lw[pr] = ll[0] | (ll[1] << 16);
  }
  uint32_t* dstb = Wp + (size_t)blk * 2048;
  *(uint4*)(dstb + (mt * 2 + 0) * 256 + lane * 4) = make_uint4(hw[0], hw[1], hw[2], hw[3]);
  *(uint4*)(dstb + (mt * 2 + 1) * 256 + lane * 4) = make_uint4(lw[0], lw[1], lw[2], lw[3]);
}

union BU { uint32_t u[4]; uint4 v; short8 s8; };

__device__ __forceinline__ void load_wchunk(const uint32_t* __restrict__ wb,
                                            BU* wh, BU* wl) {
#pragma unroll
  for (int t = 0; t < 9; ++t) {
    wh[t].v = *(const uint4*)(wb + t * 2048);
    wl[t].v = *(const uint4*)(wb + t * 2048 + 256);
  }
}

__device__ __forceinline__ void mfma_chunk(const uint32_t* __restrict__ sb,
                                           int pwbase, const BU* wh, const BU* wl,
                                           f32x16& acc) {
  const int TAPOFF[9] = {0, 1, 2, 16, 17, 18, 32, 33, 34};
#pragma unroll
  for (int tap = 0; tap < 9; ++tap) {
    const int pw = pwbase + TAPOFF[tap] * LROW;
    uint2 q0 = *(const uint2*)(sb + pw);
    uint2 q1 = *(const uint2*)(sb + pw + 2);
    uint2 q2 = *(const uint2*)(sb + pw + 4);
    uint2 q3 = *(const uint2*)(sb + pw + 6);
    BU Bh, Bl;
    Bh.u[0] = __builtin_amdgcn_perm(q0.y, q0.x, 0x07060302u);
    Bh.u[1] = __builtin_amdgcn_perm(q1.y, q1.x, 0x07060302u);
    Bh.u[2] = __builtin_amdgcn_perm(q2.y, q2.x, 0x07060302u);
    Bh.u[3] = __builtin_amdgcn_perm(q3.y, q3.x, 0x07060302u);
    Bl.u[0] = __builtin_amdgcn_perm(q0.y, q0.x, 0x05040100u);
    Bl.u[1] = __builtin_amdgcn_perm(q1.y, q1.x, 0x05040100u);
    Bl.u[2] = __builtin_amdgcn_perm(q2.y, q2.x, 0x05040100u);
    Bl.u[3] = __builtin_amdgcn_perm(q3.y, q3.x, 0x05040100u);
    acc = __builtin_amdgcn_mfma_f32_32x32x16_bf16(wh[tap].s8, Bh.s8, acc, 0, 0, 0);
    acc = __builtin_amdgcn_mfma_f32_32x32x16_bf16(wh[tap].s8, Bl.s8, acc, 0, 0, 0);
    acc = __builtin_amdgcn_mfma_f32_32x32x16_bf16(wl[tap].s8, Bh.s8, acc, 0, 0, 0);
  }
}

// Compile-time staging modes:
//  MODE 0: raw single input (stem1, external feats; plain cached loads)
//  MODE 1: kh-pair input, value = relu(A+B)  (L3-direct loads)
//  MODE 2: concat of two kh-pairs (binary conv stage 1), split at 'split'
template<int MODE>
__device__ __forceinline__ void stage_load(
    const float* __restrict__ in0A, const float* __restrict__ in0B,
    const float* __restrict__ in1A, const float* __restrict__ in1B,
    int split, int cn, int ic16, const int* imgoff, float* sv)
{
  if (MODE == 0) {
    const float* sA = in0A + (size_t)(cn * 16 + ic16) * P;
#pragma unroll
    for (int i = 0; i < 9; ++i) {
      int off = imgoff[i];
      sv[i] = (off >= 0) ? sA[off] : 0.f;
    }
  } else if (MODE == 1) {
    size_t o = (size_t)(cn * 16 + ic16) * P;
    const float* sA = in0A + o;
    const float* sB = in0B + o;
#pragma unroll
    for (int i = 0; i < 9; ++i) {
      int off = imgoff[i];
      sv[i] = (off >= 0) ? fmaxf(ld_sc0(sA + off) + ld_sc0(sB + off), 0.f) : 0.f;
    }
  } else {
    const float* sA; const float* sB;
    if (cn < split) {
      size_t o = (size_t)(cn * 16 + ic16) * P;
      sA = in0A + o; sB = in0B + o;
    } else {
      size_t o = (size_t)((cn - split) * 16 + ic16) * P;
      sA = in1A + o; sB = in1B + o;
    }
#pragma unroll
    for (int i = 0; i < 9; ++i) {
      int off = imgoff[i];
      sv[i] = (off >= 0) ? fmaxf(ld_sc0(sA + off) + ld_sc0(sB + off), 0.f) : 0.f;
    }
  }
}

// One PARTIAL conv3x3 (n chunks of 16 ic starting at cbeg, this WG's 32-oc
// slice mt) for one b. Writes raw partial sums write-through (bias added iff
// bias!=null); ReLU is applied by consumers when summing the kh pair.
template<int MODE>
__device__ __forceinline__ void conv_run(
    uint32_t sbuf[2][LBUF],
    const float* __restrict__ in0A, const float* __restrict__ in0B,
    const float* __restrict__ in1A, const float* __restrict__ in1B,
    int split, int cbeg, int n,
    int C0, int mt,
    const uint32_t* __restrict__ Wp, const float* __restrict__ bias,
    float* __restrict__ dst, float* __restrict__ dst2, float* __restrict__ zb,
    const int* imgoff)
{
  const int tid = threadIdx.x;
  const int w = tid >> 6, lane = tid & 63, l31 = lane & 31, kq = lane >> 5;
  const int ic16 = tid >> 5, pl = tid & 31;
  const int pwbase = (32 * w + l31) * LROW + kq * 8;
  const bool cw = (w < 7);
  const uint32_t* wbase = Wp + (size_t)C0 * 9 * 2048 + (mt * 2) * 256 + lane * 4;

  f32x16 acc;
#pragma unroll
  for (int i = 0; i < 16; ++i) acc[i] = 0.f;

  BU whA[9], wlA[9], whB[9], wlB[9];
  if (cw) load_wchunk(wbase + (size_t)cbeg * 9 * 2048, whA, wlA);
  { // stage chunk cbeg
    float sv[9];
    stage_load<MODE>(in0A, in0B, in1A, in1B, split, cbeg, ic16, imgoff, sv);
#pragma unroll
    for (int i = 0; i < 9; ++i) {
      int p = pl + 32 * i;
      if (p < 272) sbuf[0][p * LROW + ic16] = pack_hl(sv[i]);
    }
  }
  __syncthreads();

  int k = 0;
  while (true) {
    { // even chunk: consume A, prefetch into B
      const bool more = (k + 1 < n);
      float sv[9];
      if (more) {
        stage_load<MODE>(in0A, in0B, in1A, in1B, split, cbeg + k + 1, ic16, imgoff, sv);
        if (cw) load_wchunk(wbase + (size_t)(cbeg + k + 1) * 9 * 2048, whB, wlB);
      }
      if (cw) mfma_chunk(&sbuf[k & 1][0], pwbase, whA, wlA, acc);
      if (more) {
#pragma unroll
        for (int i = 0; i < 9; ++i) {
          int p = pl + 32 * i;
          if (p < 272) sbuf[(k + 1) & 1][p * LROW + ic16] = pack_hl(sv[i]);
        }
      }
      __syncthreads();
      if (++k >= n) break;
    }
    { // odd chunk: consume B, prefetch into A
      const bool more = (k + 1 < n);
      float sv[9];
      if (more) {
        stage_load<MODE>(in0A, in0B, in1A, in1B, split, cbeg + k + 1, ic16, imgoff, sv);
        if (cw) load_wchunk(wbase + (size_t)(cbeg + k + 1) * 9 * 2048, whA, wlA);
      }
      if (cw) mfma_chunk(&sbuf[k & 1][0], pwbase, whB, wlB, acc);
      if (more) {
#pragma unroll
        for (int i = 0; i < 9; ++i) {
          int p = pl + 32 * i;
          if (p < 272) sbuf[(k + 1) & 1][p * LROW + ic16] = pack_hl(sv[i]);
        }
      }
      __syncthreads();
      if (++k >= n) break;
    }
  }

  if (cw) {
    const int ox = l31 & 15, oy = 2 * w + (l31 >> 4);
    if (ox < 14) {
#pragma unroll
      for (int reg = 0; reg < 16; ++reg) {
        int row = (reg & 3) + 8 * (reg >> 2) + 4 * kq;
        int oc = mt * 32 + row;
        float v = acc[reg];
        if (bias) v += bias[row];
        st_sc(dst + (size_t)oc * P + oy * 14 + ox, v);
        if (dst2) st_sc(dst2 + (size_t)oc * P + oy * 14 + ox, v);
        if (zb)   st_sc(zb   + (size_t)oc * P + oy * 14 + ox, 0.f);
      }
    }
  }
}

__global__ void __launch_bounds__(512, 1) persist_kernel(
    const float* __restrict__ feats, const int* __restrict__ progs,
    const float* __restrict__ sb1, const float* __restrict__ sb2,
    const uint32_t* __restrict__ Wp,
    float* __restrict__ featA, float* __restrict__ featB,
    float* __restrict__ outbA, float* __restrict__ outbB,
    float* __restrict__ savedA, float* __restrict__ savedB,
    float* __restrict__ h1A, float* __restrict__ h1B,
    float* __restrict__ h2A, float* __restrict__ h2B,
    int* __restrict__ ctr)
{
  __shared__ uint32_t s_act[2][LBUF];
  const int tid = threadIdx.x;
  // b = bid & 31 -> all 8 slices of one b share bid%8, i.e. one XCD under
  // round-robin dispatch (locality heuristic only; correctness via L3 ops).
  const int b = blockIdx.x & 31;
  const int slice = blockIdx.x >> 5;
  const int mt = slice & 3;
  const int kh = slice >> 2;
  const size_t bo = (size_t)b * FSZ;
  int* myctr = ctr + b * 32;
  int phase = 0;

  float* featP  = kh ? featB  : featA;
  float* outbP  = kh ? outbB  : outbA;
  float* savedP = kh ? savedB : savedA;
  float* h1P    = kh ? h1B    : h1A;
  float* h2P    = kh ? h2B    : h2A;
  const float* bias1 = kh ? nullptr : sb1 + mt * 32;
  const float* bias2 = kh ? nullptr : sb2 + mt * 32;

  int imgoff[9];
#pragma unroll
  for (int i = 0; i < 9; ++i) {
    int p = (tid & 31) + 32 * i;
    int row = p >> 4, col = p & 15;
    imgoff[i] = (p < 272 && row >= 1 && row <= 14 && col >= 1 && col <= 14)
                ? (row - 1) * 14 + (col - 1) : -1;
  }

  // stem1: raw feats (1024 ic, 64 chunks -> 32 per kh) -> h1 pair
  conv_run<0>(s_act, feats + (size_t)b * 1024 * P, nullptr, nullptr, nullptr,
              1 << 28, kh * 32, 32, 0, mt, Wp, bias1,
              h1P + bo, nullptr, nullptr, imgoff);
  bbar(myctr, ++phase * 8);
  // stem2: h1 pair -> feat pair (+ outb pair init, zero saved partial)
  conv_run<1>(s_act, h1A + bo, h1B + bo, nullptr, nullptr, 1 << 28,
              kh * 4, 4, 64, mt, Wp, bias2,
              featP + bo, outbP + bo, savedP + bo, imgoff);
  bbar(myctr, ++phase * 8);

  for (int s = 0; s < NSTEP; ++s) {
    int tok = progs[b * NSTEP + (NSTEP - 1 - s)];
    int kind = KIND_TBL[tok], mi = MIDX_TBL[tok];
    if (kind == 0) continue;
    if (kind == 1) {                 // scene: saved <- out (own partial); out <- unary0(feat)
      const size_t so = bo + (size_t)mt * 32 * P;
      for (int i = tid; i < 32 * P; i += 512)
        st_sc(&savedP[so + i], ld_sc0(&outbP[so + i]));
      int C0 = 72 + mi * 16;
      conv_run<1>(s_act, featA + bo, featB + bo, nullptr, nullptr, 1 << 28,
                  kh * 4, 4, C0, mt, Wp, nullptr, h1P + bo, nullptr, nullptr, imgoff);
      bbar(myctr, ++phase * 8);
      conv_run<1>(s_act, h1A + bo, h1B + bo, nullptr, nullptr, 1 << 28,
                  kh * 4, 4, C0 + 8, mt, Wp, nullptr, outbP + bo, nullptr, nullptr, imgoff);
      bbar(myctr, ++phase * 8);
    } else if (kind == 2) {          // unary
      int C0 = 72 + mi * 16;
      conv_run<1>(s_act, outbA + bo, outbB + bo, nullptr, nullptr, 1 << 28,
                  kh * 4, 4, C0, mt, Wp, nullptr, h1P + bo, nullptr, nullptr, imgoff);
      bbar(myctr, ++phase * 8);
      conv_run<1>(s_act, h1A + bo, h1B + bo, nullptr, nullptr, 1 << 28,
                  kh * 4, 4, C0 + 8, mt, Wp, nullptr, outbP + bo, nullptr, nullptr, imgoff);
      bbar(myctr, ++phase * 8);
    } else {                         // binary: concat(out, saved) = 16 chunks, split 8/8
      int C0 = 568 + mi * 32;
      conv_run<2>(s_act, outbA + bo, outbB + bo, savedA + bo, savedB + bo, 8,
                  kh * 8, 8, C0, mt, Wp, nullptr, h1P + bo, nullptr, nullptr, imgoff);
      bbar(myctr, ++phase * 8);
      conv_run<1>(s_act, h1A + bo, h1B + bo, nullptr, nullptr, 1 << 28,
                  kh * 4, 4, C0 + 16, mt, Wp, nullptr, h2P + bo, nullptr, nullptr, imgoff);
      bbar(myctr, ++phase * 8);
      conv_run<1>(s_act, h2A + bo, h2B + bo, nullptr, nullptr, 1 << 28,
                  kh * 4, 4, C0 + 24, mt, Wp, nullptr, outbP + bo, nullptr, nullptr, imgoff);
      bbar(myctr, ++phase * 8);
    }
  }
}

// ---- tail ----
__global__ void __launch_bounds__(256) cls_pool_kernel(
    const float* __restrict__ xA, const float* __restrict__ xB,
    const float* __restrict__ Wc, const float* __restrict__ bc,
    float* __restrict__ hB)
{
  const int b = blockIdx.y, og = blockIdx.x;
  const int oc0 = og * 64;
  __shared__ float s[16 * P];
  const float* xbA = xA + (size_t)b * FSZ;
  const float* xbB = xB + (size_t)b * FSZ;
  const int tid = threadIdx.x;
  float acc[13][4];
#pragma unroll
  for (int k = 0; k < 13; ++k) { acc[k][0] = acc[k][1] = acc[k][2] = acc[k][3] = 0.f; }
  for (int c0 = 0; c0 < 128; c0 += 16) {
    __syncthreads();
    for (int i = tid; i < 16 * P; i += 256)
      s[i] = fmaxf(xbA[(size_t)c0 * P + i] + xbB[(size_t)c0 * P + i], 0.f);
    __syncthreads();
#pragma unroll
    for (int k = 0; k < 13; ++k) {
      const int idx = k * 256 + tid;
      if (idx < 64 * 49) {
        const int oc = oc0 + idx / 49, pp = idx % 49;
        const int py = pp / 7, px = pp % 7;
        const int b0 = 2 * py * 14 + 2 * px, b1 = b0 + 14;
        const float* wr = Wc + (size_t)oc * 128 + c0;
#pragma unroll
        for (int ic = 0; ic < 16; ++ic) {
          const float w = wr[ic];
          const float* sp = s + ic * P;
          const float2 r0 = *(const float2*)(sp + b0);
          const float2 r1 = *(const float2*)(sp + b1);
          acc[k][0] = fmaf(w, r0.x, acc[k][0]);
          acc[k][1] = fmaf(w, r0.y, acc[k][1]);
          acc[k][2] = fmaf(w, r1.x, acc[k][2]);
          acc[k][3] = fmaf(w, r1.y, acc[k][3]);
        }
      }
    }
  }
#pragma unroll
  for (int k = 0; k < 13; ++k) {
    const int idx = k * 256 + tid;
    if (idx < 64 * 49) {
      const int oc = oc0 + idx / 49, pp = idx % 49;
      const float m = fmaxf(fmaxf(acc[k][0], acc[k][1]), fmaxf(acc[k][2], acc[k][3]));
      hB[(size_t)b * 25088 + (size_t)oc * 49 + pp] = fmaxf(m + bc[oc], 0.f);
    }
  }
}

__global__ void __launch_bounds__(256) transpose_kernel(
    const float* __restrict__ hB, float* __restrict__ hT)
{
  __shared__ float t[256 * 33];
  const int k0 = blockIdx.x * 256;
  const int tid = threadIdx.x;
  for (int b = 0; b < 32; ++b)
    t[tid * 33 + b] = hB[(size_t)b * 25088 + k0 + tid];
  __syncthreads();
  for (int i = tid; i < 256 * 32; i += 256) {
    const int k = i >> 5, b = i & 31;
    hT[(size_t)(k0 + k) * 32 + b] = t[k * 33 + b];
  }
}

// 256 WGs: 4 oc each, 2-way K split, LDS pair-reduce.
__global__ void __launch_bounds__(256) fc1_kernel(
    const float* __restrict__ hT, const float* __restrict__ W,
    const float* __restrict__ bias, float* __restrict__ o)
{
  const int b = threadIdx.x & 31, j = threadIdx.x >> 5;   // j 0..7
  const int oc = blockIdx.x * 4 + (j & 3);
  const int kh = j >> 2;
  const float* wr = W + (size_t)oc * 25088 + (size_t)kh * 12544;
  const float* ht = hT + (size_t)kh * 12544 * 32;
  float acc = 0.f;
  for (int k = 0; k < 12544; k += 4) {
    const float4 w4 = *(const float4*)(wr + k);
    acc = fmaf(ht[(size_t)(k + 0) * 32 + b], w4.x, acc);
    acc = fmaf(ht[(size_t)(k + 1) * 32 + b], w4.y, acc);
    acc = fmaf(ht[(size_t)(k + 2) * 32 + b], w4.z, acc);
    acc = fmaf(ht[(size_t)(k + 3) * 32 + b], w4.w, acc);
  }
  __shared__ float red[8][32];
  red[j][b] = acc;
  __syncthreads();
  if (j < 4)
    o[(size_t)b * 1024 + oc] = fmaxf(red[j][b] + red[j + 4][b] + bias[oc], 0.f);
}

__global__ void __launch_bounds__(256) fc2_kernel(
    const float* __restrict__ h, const float* __restrict__ W,
    const float* __restrict__ bias, float* __restrict__ out)
{
  const int i = blockIdx.x * 256 + threadIdx.x;
  const int b = i >> 5, oo = i & 31;
  const float* wr = W + (size_t)oo * 1024;
  const float* hr = h + (size_t)b * 1024;
  float acc = bias[oo];
  for (int k = 0; k < 1024; k += 4) {
    const float4 w4 = *(const float4*)(wr + k);
    const float4 h4 = *(const float4*)(hr + k);
    acc = fmaf(h4.x, w4.x, acc);
    acc = fmaf(h4.y, w4.y, acc);
    acc = fmaf(h4.z, w4.z, acc);
    acc = fmaf(h4.w, w4.w, acc);
  }
  out[i] = acc;
}

extern "C" void kernel_launch(void* const* d_in, const int* in_sizes, int n_in,
                              void* d_out, int out_size, void* d_ws, size_t ws_size,
                              hipStream_t stream) {
  const float* feats   = (const float*)d_in[0];
  const int*   progs   = (const int*)  d_in[1];
  const float* stem_w1 = (const float*)d_in[2];
  const float* stem_b1 = (const float*)d_in[3];
  const float* stem_w2 = (const float*)d_in[4];
  const float* stem_b2 = (const float*)d_in[5];
  const float* mem_u   = (const float*)d_in[6];
  const float* mem_b   = (const float*)d_in[7];
  const float* cls_w   = (const float*)d_in[8];
  const float* cls_b   = (const float*)d_in[9];
  const float* fc1_w   = (const float*)d_in[10];
  const float* fc1_b   = (const float*)d_in[11];
  const float* fc2_w   = (const float*)d_in[12];
  const float* fc2_b   = (const float*)d_in[13];

  float* ws = (float*)d_ws;
  const size_t F = (size_t)32 * FSZ;
  float*    featA  = ws + 0 * F;
  float*    featB  = ws + 1 * F;
  float*    outbA  = ws + 2 * F;
  float*    outbB  = ws + 3 * F;
  float*    savedA = ws + 4 * F;
  float*    savedB = ws + 5 * F;
  float*    h1A    = ws + 6 * F;
  float*    h1B    = ws + 7 * F;
  float*    h2A    = ws + 8 * F;
  float*    h2B    = ws + 9 * F;
  uint32_t* Wp    = (uint32_t*)(ws + 10 * F);         // 7704 x 8KB = 63.1 MB
  int*      ctr   = (int*)(Wp + (size_t)7704 * 2048); // 32 b x 32-int lines

  hipMemsetAsync(ctr, 0, 32 * 32 * sizeof(int), stream);

  repack_kernel<<<dim3(7704), dim3(256), 0, stream>>>(stem_w1, stem_w2, mem_u, mem_b, Wp);

  persist_kernel<<<dim3(256), dim3(512), 0, stream>>>(
      feats, progs, stem_b1, stem_b2, Wp,
      featA, featB, outbA, outbB, savedA, savedB, h1A, h1B, h2A, h2B, ctr);

  float* hB   = h1A;
  float* hT   = h2A;
  float* fc1o = savedA;
  cls_pool_kernel<<<dim3(8, 32), dim3(256), 0, stream>>>(outbA, outbB, cls_w, cls_b, hB);
  transpose_kernel<<<dim3(98), dim3(256), 0, stream>>>(hB, hT);
  fc1_kernel<<<dim3(256), dim3(256), 0, stream>>>(hT, fc1_w, fc1_b, fc1o);
  fc2_kernel<<<dim3(4), dim3(256), 0, stream>>>(fc1o, fc2_w, fc2_b, (float*)d_out);
}